// Round 3
// baseline (1754.592 us; speedup 1.0000x reference)
//
#include <hip/hip_runtime.h>

#define OBS   32
#define NC    512
#define CD    16
#define HD    256
#define BATCH 8192

// ---------------------------------------------------------------------------
// Kernel 0: codebook squared norms, fp32 (prefilter) + fp64 (rerank)
// ---------------------------------------------------------------------------
__global__ void cb_norms_kernel(const float* __restrict__ cb,
                                float* __restrict__ n32, double* __restrict__ n64) {
    int c = blockIdx.x * blockDim.x + threadIdx.x;
    if (c >= NC) return;
    const float* r = cb + c * CD;
    float s32 = 0.f; double s64 = 0.0;
    #pragma unroll
    for (int j = 0; j < CD; ++j) {
        float v = r[j];
        s32 = fmaf(v, v, s32);
        s64 = fma((double)v, (double)v, s64);
    }
    n32[c] = s32; n64[c] = s64;
}

// ---------------------------------------------------------------------------
// Kernel 1: fused encoder + quantize. One block = one batch row = 32 tokens,
// processed in two halves of 16 so h0/h1 can live in LDS as fp64 (exact
// chain vs the fp64 numpy reference; argmin flips are the failure mode).
// ---------------------------------------------------------------------------
union Ovl {
    double h[16][HD];      // 32768 B : h0 then h1 for current token half
    float  cbs[NC][20];    // 40960 B : codebook fp32, 80B rows (16B-aligned,
};                         //           20-float stride => conflict-free)

__global__ void __launch_bounds__(256) encoder_kernel(
    const float* __restrict__ obs,
    const float* __restrict__ W0, const float* __restrict__ B0,
    const float* __restrict__ W1, const float* __restrict__ B1,
    const float* __restrict__ W2, const float* __restrict__ B2,
    const float* __restrict__ cb,
    const float* __restrict__ n32, const double* __restrict__ n64,
    float* __restrict__ qout)
{
    __shared__ Ovl    ovl;             // 40960 B
    __shared__ float  w1c[16][HD];     // 16384 B : W1 16-row chunk (fp32)
    __shared__ double emb64[OBS][CD];  //  4096 B
    __shared__ double redD[OBS][8];    //  2048 B
    __shared__ int    redI[OBS][8];    //  1024 B
    __shared__ double xd[OBS];         //   256 B  (total 64768 <= 65536)

    const int tid = threadIdx.x;
    const int blk = blockIdx.x;

    if (tid < OBS) xd[tid] = (double)obs[blk * OBS + tid];
    __syncthreads();

    const int jg = tid & 31;           // phase-B col group: cols jg*8..+7
    const int tg = tid >> 5;           // phase-B token group: tokens {2tg,2tg+1}
    const int t0 = tg * 2;
    const int c0 = jg * 8;
    const int s_row = tid >> 4;        // W1 staging: 16 rows x 16-col blocks
    const int s_col = (tid & 15) * 16;

    for (int half = 0; half < 2; ++half) {
        const int tb = half * 16;
        __syncthreads();               // WAR: previous half's phase-C reads done

        // ---- phase A: h0[t][j] = relu(x*W0[0,j] + W0[1+t,j] + b0[j]), fp64 ----
        {
            const int j = tid;
            const double w0j = (double)W0[j];
            const double b0j = (double)B0[j];
            for (int t = 0; t < 16; ++t) {
                double a = fma(xd[tb + t], w0j, (double)W0[(1 + tb + t) * HD + j]) + b0j;
                ovl.h[t][j] = a > 0.0 ? a : 0.0;
            }
        }

        // ---- phase B: h1 = relu(h0 @ W1 + b1), fp64 accumulate ----
        double acc[2][8];
        #pragma unroll
        for (int i = 0; i < 2; ++i)
            #pragma unroll
            for (int u = 0; u < 8; ++u) acc[i][u] = 0.0;

        for (int kc = 0; kc < 16; ++kc) {
            __syncthreads();           // covers phase-A writes (kc=0) and WAR on w1c
            {
                const float4* p = (const float4*)(W1 + (kc * 16 + s_row) * HD + s_col);
                float4 a = p[0], b = p[1], c = p[2], d = p[3];
                *(float4*)&w1c[s_row][s_col]      = a;
                *(float4*)&w1c[s_row][s_col + 4]  = b;
                *(float4*)&w1c[s_row][s_col + 8]  = c;
                *(float4*)&w1c[s_row][s_col + 12] = d;
            }
            __syncthreads();
            const int kb = kc * 16;
            #pragma unroll 4
            for (int kk = 0; kk < 16; ++kk) {
                double h0a = ovl.h[t0][kb + kk];      // 32-lane broadcast reads
                double h0b = ovl.h[t0 + 1][kb + kk];
                float4 wa = *(const float4*)&w1c[kk][c0];
                float4 wb = *(const float4*)&w1c[kk][c0 + 4];
                double w[8] = { (double)wa.x, (double)wa.y, (double)wa.z, (double)wa.w,
                                (double)wb.x, (double)wb.y, (double)wb.z, (double)wb.w };
                #pragma unroll
                for (int u = 0; u < 8; ++u) {
                    acc[0][u] = fma(h0a, w[u], acc[0][u]);
                    acc[1][u] = fma(h0b, w[u], acc[1][u]);
                }
            }
        }
        __syncthreads();               // all h0 reads done before h1 overlay

        {   // h1 = relu(acc + b1) -> ovl.h (fp64 storage)
            #pragma unroll
            for (int u = 0; u < 8; ++u) {
                double bv = (double)B1[c0 + u];
                double ha = acc[0][u] + bv;
                double hb = acc[1][u] + bv;
                ovl.h[t0][c0 + u]     = ha > 0.0 ? ha : 0.0;
                ovl.h[t0 + 1][c0 + u] = hb > 0.0 ? hb : 0.0;
            }
        }
        __syncthreads();

        // ---- phase C: emb = h1 @ W2 + b2, fp64 (thread = token x dim) ----
        {
            const int t = tid >> 4;    // local token 0..15
            const int d = tid & 15;    // dim 0..15
            double e = 0.0;
            #pragma unroll 4
            for (int k = 0; k < HD; ++k)
                e = fma(ovl.h[t][k], (double)W2[k * CD + d], e);
            emb64[tb + t][d] = e + (double)B2[d];
        }
    }
    __syncthreads();                   // last phase-C h reads done

    // stage codebook fp32 into the union area (overwrites h)
    for (int r = tid; r < NC; r += 256) {
        const float4* src = (const float4*)(cb + r * CD);
        *(float4*)&ovl.cbs[r][0]  = src[0];
        *(float4*)&ovl.cbs[r][4]  = src[1];
        *(float4*)&ovl.cbs[r][8]  = src[2];
        *(float4*)&ovl.cbs[r][12] = src[3];
    }
    __syncthreads();

    // ---- phase D: argmin_c (|c|^2 - 2 e.c); fp32 prefilter + fp64 rerank ----
    {
        const int t = tid >> 3;
        const int s = tid & 7;         // 8 lanes/token, codes ci = cc*8+s
        double e64[CD]; float e[CD];
        #pragma unroll
        for (int j = 0; j < CD; ++j) { e64[j] = emb64[t][j]; e[j] = (float)e64[j]; }

        float d1 = 3.4e38f, d2 = 3.4e38f; int i1 = 0, i2 = 1;
        for (int cc = 0; cc < 64; ++cc) {
            const int ci = cc * 8 + s;
            float4 ca = *(const float4*)&ovl.cbs[ci][0];
            float4 cb4 = *(const float4*)&ovl.cbs[ci][4];
            float4 cc4 = *(const float4*)&ovl.cbs[ci][8];
            float4 cd4 = *(const float4*)&ovl.cbs[ci][12];
            float dA = 0.f, dB = 0.f;
            dA = fmaf(ca.x,  e[0],  dA); dB = fmaf(ca.y,  e[1],  dB);
            dA = fmaf(ca.z,  e[2],  dA); dB = fmaf(ca.w,  e[3],  dB);
            dA = fmaf(cb4.x, e[4],  dA); dB = fmaf(cb4.y, e[5],  dB);
            dA = fmaf(cb4.z, e[6],  dA); dB = fmaf(cb4.w, e[7],  dB);
            dA = fmaf(cc4.x, e[8],  dA); dB = fmaf(cc4.y, e[9],  dB);
            dA = fmaf(cc4.z, e[10], dA); dB = fmaf(cc4.w, e[11], dB);
            dA = fmaf(cd4.x, e[12], dA); dB = fmaf(cd4.y, e[13], dB);
            dA = fmaf(cd4.z, e[14], dA); dB = fmaf(cd4.w, e[15], dB);
            float d = fmaf(-2.f, dA + dB, n32[ci]);
            if (d < d1)      { d2 = d1; i2 = i1; d1 = d; i1 = ci; }
            else if (d < d2) { d2 = d;  i2 = ci; }
        }
        // fp64 rerank of the lane's two candidates
        double s1 = 0.0, s2 = 0.0;
        #pragma unroll
        for (int j = 0; j < CD; ++j) {
            s1 = fma(e64[j], (double)ovl.cbs[i1][j], s1);
            s2 = fma(e64[j], (double)ovl.cbs[i2][j], s2);
        }
        double D1 = n64[i1] - 2.0 * s1;
        double D2 = n64[i2] - 2.0 * s2;
        double Db; int ib;
        if (D2 < D1 || (D2 == D1 && i2 < i1)) { Db = D2; ib = i2; }
        else                                  { Db = D1; ib = i1; }
        redD[t][s] = Db;
        redI[t][s] = ib;
    }
    __syncthreads();

    if (tid < OBS) {                   // reduce 8 lanes per token, tie->low idx
        const int t = tid;
        double Db = redD[t][0]; int ib = redI[t][0];
        #pragma unroll
        for (int s = 1; s < 8; ++s) {
            double D = redD[t][s]; int I = redI[t][s];
            if (D < Db || (D == Db && I < ib)) { Db = D; ib = I; }
        }
        float* dstq = qout + (blk * OBS + t) * CD;
        const float* srcq = &ovl.cbs[ib][0];
        *(float4*)&dstq[0]  = *(const float4*)&srcq[0];
        *(float4*)&dstq[4]  = *(const float4*)&srcq[4];
        *(float4*)&dstq[8]  = *(const float4*)&srcq[8];
        *(float4*)&dstq[12] = *(const float4*)&srcq[12];
    }
}

// ---------------------------------------------------------------------------
// Kernel 2: decoder MLP 512 -> 256 -> 256 -> 32, 16 batch rows per block.
// fp32 throughout (2% output tolerance; input rows are exact codebook rows).
// ---------------------------------------------------------------------------
__global__ void __launch_bounds__(256) decoder_kernel(
    const float* __restrict__ qin,
    const float* __restrict__ W0, const float* __restrict__ B0,
    const float* __restrict__ W1, const float* __restrict__ B1,
    const float* __restrict__ W2, const float* __restrict__ B2,
    float* __restrict__ out)
{
    __shared__ float qb[16][512];   // 32 KB: q, later reused as h2[16][256]
    __shared__ float hb[16][256];   // 16 KB
    const int tid = threadIdx.x;
    const int row0 = blockIdx.x * 16;

    {   // stage q, 32 contiguous floats per thread
        const int fl = tid * 32;
        const int r  = fl >> 9;
        const int c0 = fl & 511;
        const float4* src = (const float4*)(qin + row0 * 512 + fl);
        float4* dst = (float4*)&qb[r][c0];
        #pragma unroll
        for (int q4 = 0; q4 < 8; ++q4) dst[q4] = src[q4];
    }
    __syncthreads();

    const int jg = tid & 63, tg = tid >> 6;
    const int j0 = jg * 4, r0 = tg * 4;

    // ---- layer 0: K=512 ----
    {
        float acA[4][4], acB[4][4];
        #pragma unroll
        for (int tt = 0; tt < 4; ++tt)
            #pragma unroll
            for (int u = 0; u < 4; ++u) { acA[tt][u] = 0.f; acB[tt][u] = 0.f; }
        for (int k = 0; k < 512; k += 4) {
            float hr[4][4];
            #pragma unroll
            for (int tt = 0; tt < 4; ++tt) {
                float4 hv = *(const float4*)&qb[r0 + tt][k];
                hr[tt][0] = hv.x; hr[tt][1] = hv.y; hr[tt][2] = hv.z; hr[tt][3] = hv.w;
            }
            #pragma unroll
            for (int p = 0; p < 4; ++p) {
                float4 w = *(const float4*)(W0 + (k + p) * 256 + j0);
                if (p < 2) {
                    #pragma unroll
                    for (int tt = 0; tt < 4; ++tt) {
                        acA[tt][0] = fmaf(hr[tt][p], w.x, acA[tt][0]);
                        acA[tt][1] = fmaf(hr[tt][p], w.y, acA[tt][1]);
                        acA[tt][2] = fmaf(hr[tt][p], w.z, acA[tt][2]);
                        acA[tt][3] = fmaf(hr[tt][p], w.w, acA[tt][3]);
                    }
                } else {
                    #pragma unroll
                    for (int tt = 0; tt < 4; ++tt) {
                        acB[tt][0] = fmaf(hr[tt][p], w.x, acB[tt][0]);
                        acB[tt][1] = fmaf(hr[tt][p], w.y, acB[tt][1]);
                        acB[tt][2] = fmaf(hr[tt][p], w.z, acB[tt][2]);
                        acB[tt][3] = fmaf(hr[tt][p], w.w, acB[tt][3]);
                    }
                }
            }
        }
        #pragma unroll
        for (int tt = 0; tt < 4; ++tt)
            #pragma unroll
            for (int u = 0; u < 4; ++u)
                hb[r0 + tt][j0 + u] = fmaxf((acA[tt][u] + acB[tt][u]) + B0[j0 + u], 0.f);
    }
    __syncthreads();

    // ---- layer 1: K=256, write h2 into qb storage ----
    float* h2 = &qb[0][0];
    {
        float acA[4][4], acB[4][4];
        #pragma unroll
        for (int tt = 0; tt < 4; ++tt)
            #pragma unroll
            for (int u = 0; u < 4; ++u) { acA[tt][u] = 0.f; acB[tt][u] = 0.f; }
        for (int k = 0; k < 256; k += 4) {
            float hr[4][4];
            #pragma unroll
            for (int tt = 0; tt < 4; ++tt) {
                float4 hv = *(const float4*)&hb[r0 + tt][k];
                hr[tt][0] = hv.x; hr[tt][1] = hv.y; hr[tt][2] = hv.z; hr[tt][3] = hv.w;
            }
            #pragma unroll
            for (int p = 0; p < 4; ++p) {
                float4 w = *(const float4*)(W1 + (k + p) * 256 + j0);
                if (p < 2) {
                    #pragma unroll
                    for (int tt = 0; tt < 4; ++tt) {
                        acA[tt][0] = fmaf(hr[tt][p], w.x, acA[tt][0]);
                        acA[tt][1] = fmaf(hr[tt][p], w.y, acA[tt][1]);
                        acA[tt][2] = fmaf(hr[tt][p], w.z, acA[tt][2]);
                        acA[tt][3] = fmaf(hr[tt][p], w.w, acA[tt][3]);
                    }
                } else {
                    #pragma unroll
                    for (int tt = 0; tt < 4; ++tt) {
                        acB[tt][0] = fmaf(hr[tt][p], w.x, acB[tt][0]);
                        acB[tt][1] = fmaf(hr[tt][p], w.y, acB[tt][1]);
                        acB[tt][2] = fmaf(hr[tt][p], w.z, acB[tt][2]);
                        acB[tt][3] = fmaf(hr[tt][p], w.w, acB[tt][3]);
                    }
                }
            }
        }
        __syncthreads();               // layer-0 qb reads fully done (paranoia)
        #pragma unroll
        for (int tt = 0; tt < 4; ++tt)
            #pragma unroll
            for (int u = 0; u < 4; ++u)
                h2[(r0 + tt) * 256 + j0 + u] =
                    fmaxf((acA[tt][u] + acB[tt][u]) + B1[j0 + u], 0.f);
    }
    __syncthreads();

    // ---- layer 2: N=32 output, no relu ----
    {
        const int c  = tid & 31;
        const int rg = tid >> 5;
        for (int rr = rg; rr < 16; rr += 8) {
            float a0 = 0.f, a1 = 0.f, a2 = 0.f, a3 = 0.f;
            #pragma unroll 4
            for (int k = 0; k < 256; k += 4) {
                float4 hv = *(const float4*)&h2[rr * 256 + k];
                a0 = fmaf(hv.x, W2[(k + 0) * 32 + c], a0);
                a1 = fmaf(hv.y, W2[(k + 1) * 32 + c], a1);
                a2 = fmaf(hv.z, W2[(k + 2) * 32 + c], a2);
                a3 = fmaf(hv.w, W2[(k + 3) * 32 + c], a3);
            }
            out[(row0 + rr) * 32 + c] = ((a0 + a1) + (a2 + a3)) + B2[c];
        }
    }
}

// ---------------------------------------------------------------------------
extern "C" void kernel_launch(void* const* d_in, const int* in_sizes, int n_in,
                              void* d_out, int out_size, void* d_ws, size_t ws_size,
                              hipStream_t stream) {
    (void)in_sizes; (void)n_in; (void)out_size; (void)ws_size;
    const float* obs = (const float*)d_in[0];
    const float* eW0 = (const float*)d_in[1];
    const float* eb0 = (const float*)d_in[2];
    const float* eW1 = (const float*)d_in[3];
    const float* eb1 = (const float*)d_in[4];
    const float* eW2 = (const float*)d_in[5];
    const float* eb2 = (const float*)d_in[6];
    const float* dW0 = (const float*)d_in[7];
    const float* db0 = (const float*)d_in[8];
    const float* dW1 = (const float*)d_in[9];
    const float* db1 = (const float*)d_in[10];
    const float* dW2 = (const float*)d_in[11];
    const float* db2 = (const float*)d_in[12];
    const float* cb  = (const float*)d_in[13];

    char*   ws   = (char*)d_ws;
    float*  n32  = (float*)ws;                 // 512 * 4B
    double* n64  = (double*)(ws + 4096);       // 512 * 8B
    float*  qbuf = (float*)(ws + 8192);        // 262144 * 16 fp32 = 16 MB

    cb_norms_kernel<<<2, 256, 0, stream>>>(cb, n32, n64);
    encoder_kernel<<<BATCH, 256, 0, stream>>>(obs, eW0, eb0, eW1, eb1, eW2, eb2,
                                              cb, n32, n64, qbuf);
    decoder_kernel<<<BATCH / 16, 256, 0, stream>>>(qbuf, dW0, db0, dW1, db1,
                                                   dW2, db2, (float*)d_out);
}

// Round 4
// 735.500 us; speedup vs baseline: 2.3856x; 2.3856x over previous
//
#include <hip/hip_runtime.h>

#define OBS   32
#define NC    512
#define CD    16
#define HD    256
#define BATCH 8192
#define EPS   4e-3f

// ---------------------------------------------------------------------------
// Kernel 0: codebook squared norms (fp32 + fp64) and flag-counter zeroing.
// ---------------------------------------------------------------------------
__global__ void cb_norms_kernel(const float* __restrict__ cb,
                                float* __restrict__ n32, double* __restrict__ n64,
                                int* __restrict__ fcnt) {
    if (blockIdx.x == 0 && threadIdx.x == 0) *fcnt = 0;
    int c = blockIdx.x * blockDim.x + threadIdx.x;
    if (c >= NC) return;
    const float* r = cb + c * CD;
    float s32 = 0.f; double s64 = 0.0;
    #pragma unroll
    for (int j = 0; j < CD; ++j) {
        float v = r[j];
        s32 = fmaf(v, v, s32);
        s64 = fma((double)v, (double)v, s64);
    }
    n32[c] = s32; n64[c] = s64;
}

// ---------------------------------------------------------------------------
// Kernel 1: fp32 fused encoder + quantize prefilter. One block = one batch
// row (32 tokens). Exact fp32 top-2 + gap; tokens with gap < EPS are flagged
// for the fp64 fixup kernel. h rows padded to 260 floats (conflict-free);
// codebook LDS stride 20 (5 coprime 32 -> conflict-free 32-lane striping).
// ---------------------------------------------------------------------------
__global__ void __launch_bounds__(256, 3) encoder_kernel(
    const float* __restrict__ obs,
    const float* __restrict__ W0, const float* __restrict__ B0,
    const float* __restrict__ W1, const float* __restrict__ B1,
    const float* __restrict__ W2, const float* __restrict__ B2,
    const float* __restrict__ cb, const float* __restrict__ n32,
    int* __restrict__ idxbuf, int* __restrict__ fcnt, int* __restrict__ flist)
{
    // smem layout: [0..8319] hbuf (32 rows x 260), [8320..12479] wst
    // (W1 16-row chunk [16][256], later W2t [16][260]).
    // Phase D overlays smem as cbs[512][20].
    __shared__ float smem[12480];       // 49920 B
    __shared__ float embs[OBS * CD];    //  2048 B
    __shared__ float xrow[OBS];         //   128 B   (total 52096 B)
    float* const wst = smem + 8320;

    const int tid = threadIdx.x;
    const int blk = blockIdx.x;

    if (tid < OBS) xrow[tid] = obs[blk * OBS + tid];
    __syncthreads();

    // ---- phase A: h0[t][j] = relu(x_t*W0[0,j] + W0[1+t,j] + b0[j]) ----
    {
        const int j = tid;
        const float w0j = W0[j];
        const float b0j = B0[j];
        for (int t = 0; t < OBS; ++t) {
            float pre = fmaf(xrow[t], w0j, W0[(1 + t) * HD + j]) + b0j;
            smem[t * 260 + j] = fmaxf(pre, 0.f);
        }
    }

    // ---- phase B: h1 = relu(h0 @ W1 + b1); thread tile 8 tokens x 4 cols ----
    const int c0 = (tid & 63) * 4;      // 64 col groups
    const int t0 = (tid >> 6) * 8;      // 4 token groups (wave-uniform)
    const int s_row = tid >> 4;         // W1 staging: 16 rows x 16-col blocks
    const int s_col = (tid & 15) * 16;

    float acc[8][4];
    #pragma unroll
    for (int tt = 0; tt < 8; ++tt)
        #pragma unroll
        for (int u = 0; u < 4; ++u) acc[tt][u] = 0.f;

    for (int kc = 0; kc < 16; ++kc) {
        __syncthreads();                // phase-A done (kc=0) / WAR on wst
        {
            const float4* p = (const float4*)(W1 + (kc * 16 + s_row) * HD + s_col);
            float4 a = p[0], b = p[1], c = p[2], d = p[3];
            float4* dst = (float4*)(wst + s_row * HD + s_col);
            dst[0] = a; dst[1] = b; dst[2] = c; dst[3] = d;
        }
        __syncthreads();
        #pragma unroll
        for (int k4 = 0; k4 < 4; ++k4) {
            const int kb = kc * 16 + k4 * 4;
            float4 hv[8];
            #pragma unroll
            for (int tt = 0; tt < 8; ++tt)     // wave-uniform rows: broadcast
                hv[tt] = *(const float4*)&smem[(t0 + tt) * 260 + kb];
            #pragma unroll
            for (int q = 0; q < 4; ++q) {
                float4 w = *(const float4*)(wst + (k4 * 4 + q) * HD + c0);
                #pragma unroll
                for (int tt = 0; tt < 8; ++tt) {
                    float h = (q == 0) ? hv[tt].x : (q == 1) ? hv[tt].y
                             : (q == 2) ? hv[tt].z : hv[tt].w;
                    acc[tt][0] = fmaf(h, w.x, acc[tt][0]);
                    acc[tt][1] = fmaf(h, w.y, acc[tt][1]);
                    acc[tt][2] = fmaf(h, w.z, acc[tt][2]);
                    acc[tt][3] = fmaf(h, w.w, acc[tt][3]);
                }
            }
        }
    }
    __syncthreads();                    // all h0 / wst reads done

    {   // h1 = relu(acc + b1) -> hbuf; also stage W2^T into wst
        float4 b1v = *(const float4*)(B1 + c0);
        #pragma unroll
        for (int tt = 0; tt < 8; ++tt) {
            float4 o;
            o.x = fmaxf(acc[tt][0] + b1v.x, 0.f);
            o.y = fmaxf(acc[tt][1] + b1v.y, 0.f);
            o.z = fmaxf(acc[tt][2] + b1v.z, 0.f);
            o.w = fmaxf(acc[tt][3] + b1v.w, 0.f);
            *(float4*)&smem[(t0 + tt) * 260 + c0] = o;
        }
        const int d = tid & 15, k0 = (tid >> 4) * 16;
        #pragma unroll
        for (int i = 0; i < 16; ++i)
            wst[d * 260 + k0 + i] = W2[(k0 + i) * CD + d];
    }
    __syncthreads();

    // ---- phase C: emb = h1 @ W2 + b2 (thread = token x 2 dims) ----
    {
        const int t  = tid >> 3;
        const int d0 = tid & 7;
        float a[4] = {0, 0, 0, 0}, b[4] = {0, 0, 0, 0};
        #pragma unroll 4
        for (int k4 = 0; k4 < 64; ++k4) {
            float4 h  = *(const float4*)&smem[t * 260 + k4 * 4];
            float4 wA = *(const float4*)(wst + d0 * 260 + k4 * 4);
            float4 wB = *(const float4*)(wst + (d0 + 8) * 260 + k4 * 4);
            a[0] = fmaf(h.x, wA.x, a[0]); a[1] = fmaf(h.y, wA.y, a[1]);
            a[2] = fmaf(h.z, wA.z, a[2]); a[3] = fmaf(h.w, wA.w, a[3]);
            b[0] = fmaf(h.x, wB.x, b[0]); b[1] = fmaf(h.y, wB.y, b[1]);
            b[2] = fmaf(h.z, wB.z, b[2]); b[3] = fmaf(h.w, wB.w, b[3]);
        }
        embs[t * CD + d0]     = ((a[0] + a[1]) + (a[2] + a[3])) + B2[d0];
        embs[t * CD + d0 + 8] = ((b[0] + b[1]) + (b[2] + b[3])) + B2[d0 + 8];
    }
    __syncthreads();                    // emb done; h1/W2t reads done

    // stage codebook into smem overlay, stride 20 floats
    for (int r = tid; r < NC; r += 256) {
        const float4* src = (const float4*)(cb + r * CD);
        float4 A = src[0], B4 = src[1], C4 = src[2], D4 = src[3];
        *(float4*)&smem[r * 20 + 0]  = A;
        *(float4*)&smem[r * 20 + 4]  = B4;
        *(float4*)&smem[r * 20 + 8]  = C4;
        *(float4*)&smem[r * 20 + 12] = D4;
    }
    __syncthreads();

    // ---- phase D: exact fp32 top-2 over 512 codes; flag near-ties ----
    {
        const int s  = tid & 31;        // 32 lanes/token-group, 16 codes each
        const int tD = (tid >> 5) * 4;  // 4 tokens per thread
        float e[4][CD];
        #pragma unroll
        for (int j = 0; j < 4; ++j)
            #pragma unroll
            for (int q4 = 0; q4 < 4; ++q4) {
                float4 v = *(const float4*)&embs[(tD + j) * CD + q4 * 4];
                e[j][q4 * 4 + 0] = v.x; e[j][q4 * 4 + 1] = v.y;
                e[j][q4 * 4 + 2] = v.z; e[j][q4 * 4 + 3] = v.w;
            }
        float d1[4], d2[4]; int i1[4], i2[4];
        #pragma unroll
        for (int j = 0; j < 4; ++j) { d1[j] = d2[j] = 3.4e38f; i1[j] = i2[j] = 0x7fffffff; }

        for (int cc = 0; cc < 16; ++cc) {
            const int ci = cc * 32 + s;
            float4 A  = *(const float4*)&smem[ci * 20 + 0];
            float4 B4 = *(const float4*)&smem[ci * 20 + 4];
            float4 C4 = *(const float4*)&smem[ci * 20 + 8];
            float4 D4 = *(const float4*)&smem[ci * 20 + 12];
            float cn = n32[ci];
            #pragma unroll
            for (int j = 0; j < 4; ++j) {
                float dA = 0.f, dB = 0.f;
                dA = fmaf(A.x,  e[j][0],  dA); dB = fmaf(A.y,  e[j][1],  dB);
                dA = fmaf(A.z,  e[j][2],  dA); dB = fmaf(A.w,  e[j][3],  dB);
                dA = fmaf(B4.x, e[j][4],  dA); dB = fmaf(B4.y, e[j][5],  dB);
                dA = fmaf(B4.z, e[j][6],  dA); dB = fmaf(B4.w, e[j][7],  dB);
                dA = fmaf(C4.x, e[j][8],  dA); dB = fmaf(C4.y, e[j][9],  dB);
                dA = fmaf(C4.z, e[j][10], dA); dB = fmaf(C4.w, e[j][11], dB);
                dA = fmaf(D4.x, e[j][12], dA); dB = fmaf(D4.y, e[j][13], dB);
                dA = fmaf(D4.z, e[j][14], dA); dB = fmaf(D4.w, e[j][15], dB);
                float d = fmaf(-2.f, dA + dB, cn);
                if (d < d1[j])      { d2[j] = d1[j]; i2[j] = i1[j]; d1[j] = d; i1[j] = ci; }
                else if (d < d2[j]) { d2[j] = d;  i2[j] = ci; }
            }
        }
        // width-32 top-2 merge reduce (tie -> low index)
        #pragma unroll
        for (int off = 16; off >= 1; off >>= 1) {
            #pragma unroll
            for (int j = 0; j < 4; ++j) {
                float od1 = __shfl_down(d1[j], off, 32);
                int   oi1 = __shfl_down(i1[j], off, 32);
                float od2 = __shfl_down(d2[j], off, 32);
                int   oi2 = __shfl_down(i2[j], off, 32);
                bool ob = (od1 < d1[j]) || (od1 == d1[j] && oi1 < i1[j]);
                float n1d, n2d; int n1i, n2i;
                if (ob) {
                    n1d = od1; n1i = oi1;
                    bool t2 = (d1[j] < od2) || (d1[j] == od2 && i1[j] < oi2);
                    n2d = t2 ? d1[j] : od2; n2i = t2 ? i1[j] : oi2;
                } else {
                    n1d = d1[j]; n1i = i1[j];
                    bool t2 = (od1 < d2[j]) || (od1 == d2[j] && oi1 < i2[j]);
                    n2d = t2 ? od1 : d2[j]; n2i = t2 ? oi1 : i2[j];
                }
                d1[j] = n1d; i1[j] = n1i; d2[j] = n2d; i2[j] = n2i;
            }
        }
        if (s == 0) {
            int nf = 0, ft[4];
            #pragma unroll
            for (int j = 0; j < 4; ++j) {
                int T = blk * OBS + tD + j;
                idxbuf[T] = i1[j];
                if (d2[j] - d1[j] < EPS) ft[nf++] = T;
            }
            if (nf) {
                int base = atomicAdd(fcnt, nf);
                for (int k = 0; k < nf; ++k) flist[base + k] = ft[k];
            }
        }
    }
}

// ---------------------------------------------------------------------------
// Kernel 2: fp64 exact re-solve for flagged (near-tie) tokens. One block per
// flagged token, grid-stride. Overwrites idxbuf[T] with the fp64 argmin.
// ---------------------------------------------------------------------------
__global__ void __launch_bounds__(256) fixup_kernel(
    const float* __restrict__ obs,
    const float* __restrict__ W0, const float* __restrict__ B0,
    const float* __restrict__ W1, const float* __restrict__ B1,
    const float* __restrict__ W2, const float* __restrict__ B2,
    const float* __restrict__ cb, const double* __restrict__ n64,
    const int* __restrict__ fcnt, const int* __restrict__ flist,
    int* __restrict__ idxbuf)
{
    __shared__ double h0s[HD];
    __shared__ double h1s[HD];
    __shared__ double ep[16][17];
    __shared__ double es[CD];
    __shared__ double dmin[256];
    __shared__ int    imin[256];

    int n = *fcnt;
    if (n > BATCH * OBS) n = BATCH * OBS;
    const int j = threadIdx.x;

    for (int f = blockIdx.x; f < n; f += gridDim.x) {
        const int T = flist[f];
        const int b = T >> 5, t = T & 31;
        const double x = (double)obs[b * OBS + t];
        {
            double a = fma(x, (double)W0[j], (double)W0[(1 + t) * HD + j])
                     + (double)B0[j];
            h0s[j] = a > 0.0 ? a : 0.0;
        }
        __syncthreads();
        {
            double s = 0.0;
            for (int k = 0; k < HD; ++k)
                s = fma(h0s[k], (double)W1[k * HD + j], s);
            s += (double)B1[j];
            h1s[j] = s > 0.0 ? s : 0.0;
        }
        __syncthreads();
        {
            const int d = j & 15, part = j >> 4;
            double s = 0.0;
            for (int k = part * 16; k < part * 16 + 16; ++k)
                s = fma(h1s[k], (double)W2[k * CD + d], s);
            ep[part][d] = s;
        }
        __syncthreads();
        if (j < CD) {
            double s = 0.0;
            for (int p = 0; p < 16; ++p) s += ep[p][j];
            es[j] = s + (double)B2[j];
        }
        __syncthreads();
        {
            double best = 1e300; int bi = 0x7fffffff;
            for (int c = j; c < NC; c += 256) {
                double dot = 0.0;
                #pragma unroll
                for (int q = 0; q < CD; ++q)
                    dot = fma(es[q], (double)cb[c * CD + q], dot);
                double D = n64[c] - 2.0 * dot;
                if (D < best || (D == best && c < bi)) { best = D; bi = c; }
            }
            dmin[j] = best; imin[j] = bi;
        }
        __syncthreads();
        if (j == 0) {
            double best = dmin[0]; int bi = imin[0];
            for (int k = 1; k < 256; ++k)
                if (dmin[k] < best || (dmin[k] == best && imin[k] < bi)) {
                    best = dmin[k]; bi = imin[k];
                }
            idxbuf[T] = bi;
        }
        __syncthreads();
    }
}

// ---------------------------------------------------------------------------
// Kernel 3: decoder MLP 512 -> 256 -> 256 -> 32, 16 batch rows per block.
// Gathers q rows from the codebook via idxbuf (q never materialized).
// ---------------------------------------------------------------------------
__global__ void __launch_bounds__(256) decoder_kernel(
    const int* __restrict__ idx, const float* __restrict__ cbk,
    const float* __restrict__ W0, const float* __restrict__ B0,
    const float* __restrict__ W1, const float* __restrict__ B1,
    const float* __restrict__ W2, const float* __restrict__ B2,
    float* __restrict__ out)
{
    __shared__ float qb[16][512];   // 32 KB: q, later reused as h2[16][256]
    __shared__ float hb[16][256];   // 16 KB
    const int tid = threadIdx.x;
    const int row0 = blockIdx.x * 16;

    {   // gather q rows: 2 tokens per thread from L1-resident codebook
        const int base = row0 * OBS;
        #pragma unroll
        for (int m = 0; m < 2; ++m) {
            int g = tid * 2 + m;
            int ciq = idx[base + g];
            const float4* src = (const float4*)(cbk + ciq * CD);
            float4* dst = (float4*)&qb[g >> 5][(g & 31) * CD];
            dst[0] = src[0]; dst[1] = src[1]; dst[2] = src[2]; dst[3] = src[3];
        }
    }
    __syncthreads();

    const int jg = tid & 63, tg = tid >> 6;
    const int j0 = jg * 4, r0 = tg * 4;

    // ---- layer 0: K=512 ----
    {
        float acA[4][4], acB[4][4];
        #pragma unroll
        for (int tt = 0; tt < 4; ++tt)
            #pragma unroll
            for (int u = 0; u < 4; ++u) { acA[tt][u] = 0.f; acB[tt][u] = 0.f; }
        for (int k = 0; k < 512; k += 4) {
            float hr[4][4];
            #pragma unroll
            for (int tt = 0; tt < 4; ++tt) {
                float4 hv = *(const float4*)&qb[r0 + tt][k];
                hr[tt][0] = hv.x; hr[tt][1] = hv.y; hr[tt][2] = hv.z; hr[tt][3] = hv.w;
            }
            #pragma unroll
            for (int p = 0; p < 4; ++p) {
                float4 w = *(const float4*)(W0 + (k + p) * 256 + j0);
                if (p < 2) {
                    #pragma unroll
                    for (int tt = 0; tt < 4; ++tt) {
                        acA[tt][0] = fmaf(hr[tt][p], w.x, acA[tt][0]);
                        acA[tt][1] = fmaf(hr[tt][p], w.y, acA[tt][1]);
                        acA[tt][2] = fmaf(hr[tt][p], w.z, acA[tt][2]);
                        acA[tt][3] = fmaf(hr[tt][p], w.w, acA[tt][3]);
                    }
                } else {
                    #pragma unroll
                    for (int tt = 0; tt < 4; ++tt) {
                        acB[tt][0] = fmaf(hr[tt][p], w.x, acB[tt][0]);
                        acB[tt][1] = fmaf(hr[tt][p], w.y, acB[tt][1]);
                        acB[tt][2] = fmaf(hr[tt][p], w.z, acB[tt][2]);
                        acB[tt][3] = fmaf(hr[tt][p], w.w, acB[tt][3]);
                    }
                }
            }
        }
        #pragma unroll
        for (int tt = 0; tt < 4; ++tt)
            #pragma unroll
            for (int u = 0; u < 4; ++u)
                hb[r0 + tt][j0 + u] = fmaxf((acA[tt][u] + acB[tt][u]) + B0[j0 + u], 0.f);
    }
    __syncthreads();

    // ---- layer 1: K=256, write h2 into qb storage ----
    float* h2 = &qb[0][0];
    {
        float acA[4][4], acB[4][4];
        #pragma unroll
        for (int tt = 0; tt < 4; ++tt)
            #pragma unroll
            for (int u = 0; u < 4; ++u) { acA[tt][u] = 0.f; acB[tt][u] = 0.f; }
        for (int k = 0; k < 256; k += 4) {
            float hr[4][4];
            #pragma unroll
            for (int tt = 0; tt < 4; ++tt) {
                float4 hv = *(const float4*)&hb[r0 + tt][k];
                hr[tt][0] = hv.x; hr[tt][1] = hv.y; hr[tt][2] = hv.z; hr[tt][3] = hv.w;
            }
            #pragma unroll
            for (int p = 0; p < 4; ++p) {
                float4 w = *(const float4*)(W1 + (k + p) * 256 + j0);
                if (p < 2) {
                    #pragma unroll
                    for (int tt = 0; tt < 4; ++tt) {
                        acA[tt][0] = fmaf(hr[tt][p], w.x, acA[tt][0]);
                        acA[tt][1] = fmaf(hr[tt][p], w.y, acA[tt][1]);
                        acA[tt][2] = fmaf(hr[tt][p], w.z, acA[tt][2]);
                        acA[tt][3] = fmaf(hr[tt][p], w.w, acA[tt][3]);
                    }
                } else {
                    #pragma unroll
                    for (int tt = 0; tt < 4; ++tt) {
                        acB[tt][0] = fmaf(hr[tt][p], w.x, acB[tt][0]);
                        acB[tt][1] = fmaf(hr[tt][p], w.y, acB[tt][1]);
                        acB[tt][2] = fmaf(hr[tt][p], w.z, acB[tt][2]);
                        acB[tt][3] = fmaf(hr[tt][p], w.w, acB[tt][3]);
                    }
                }
            }
        }
        __syncthreads();
        #pragma unroll
        for (int tt = 0; tt < 4; ++tt)
            #pragma unroll
            for (int u = 0; u < 4; ++u)
                h2[(r0 + tt) * 256 + j0 + u] =
                    fmaxf((acA[tt][u] + acB[tt][u]) + B1[j0 + u], 0.f);
    }
    __syncthreads();

    // ---- layer 2: N=32 output, no relu ----
    {
        const int c  = tid & 31;
        const int rg = tid >> 5;
        for (int rr = rg; rr < 16; rr += 8) {
            float a0 = 0.f, a1 = 0.f, a2 = 0.f, a3 = 0.f;
            #pragma unroll 4
            for (int k = 0; k < 256; k += 4) {
                float4 hv = *(const float4*)&h2[rr * 256 + k];
                a0 = fmaf(hv.x, W2[(k + 0) * 32 + c], a0);
                a1 = fmaf(hv.y, W2[(k + 1) * 32 + c], a1);
                a2 = fmaf(hv.z, W2[(k + 2) * 32 + c], a2);
                a3 = fmaf(hv.w, W2[(k + 3) * 32 + c], a3);
            }
            out[(row0 + rr) * 32 + c] = ((a0 + a1) + (a2 + a3)) + B2[c];
        }
    }
}

// ---------------------------------------------------------------------------
extern "C" void kernel_launch(void* const* d_in, const int* in_sizes, int n_in,
                              void* d_out, int out_size, void* d_ws, size_t ws_size,
                              hipStream_t stream) {
    (void)in_sizes; (void)n_in; (void)out_size; (void)ws_size;
    const float* obs = (const float*)d_in[0];
    const float* eW0 = (const float*)d_in[1];
    const float* eb0 = (const float*)d_in[2];
    const float* eW1 = (const float*)d_in[3];
    const float* eb1 = (const float*)d_in[4];
    const float* eW2 = (const float*)d_in[5];
    const float* eb2 = (const float*)d_in[6];
    const float* dW0 = (const float*)d_in[7];
    const float* db0 = (const float*)d_in[8];
    const float* dW1 = (const float*)d_in[9];
    const float* db1 = (const float*)d_in[10];
    const float* dW2 = (const float*)d_in[11];
    const float* db2 = (const float*)d_in[12];
    const float* cb  = (const float*)d_in[13];

    char*   ws    = (char*)d_ws;
    float*  n32   = (float*)ws;                          // 2 KB
    double* n64   = (double*)(ws + 4096);                // 4 KB
    int*    fcnt  = (int*)(ws + 8192);                   // 4 B
    int*    flist = (int*)(ws + 8448);                   // 1 MB (worst case)
    int*    idxb  = (int*)(ws + 8448 + 1048576);         // 1 MB

    cb_norms_kernel<<<2, 256, 0, stream>>>(cb, n32, n64, fcnt);
    encoder_kernel<<<BATCH, 256, 0, stream>>>(obs, eW0, eb0, eW1, eb1, eW2, eb2,
                                              cb, n32, idxb, fcnt, flist);
    fixup_kernel<<<256, 256, 0, stream>>>(obs, eW0, eb0, eW1, eb1, eW2, eb2,
                                          cb, n64, fcnt, flist, idxb);
    decoder_kernel<<<BATCH / 16, 256, 0, stream>>>(idxb, cb, dW0, db0, dW1, db1,
                                                   dW2, db2, (float*)d_out);
}